// Round 17
// baseline (414.774 us; speedup 1.0000x reference)
//
#include <hip/hip_runtime.h>
#include <stdint.h>

#define N_GENE 20000
#define N_DRUG 3000
#define D_GENE 1024
#define D_DRUG 512
#define H0 256
#define H1 128
#define E_GG 600000
#define E_DD 120000
#define E_DT 150000

typedef __attribute__((ext_vector_type(8))) short bf16x8;
typedef __attribute__((ext_vector_type(4))) float f32x4;

// ---------------- Threefry-2x32 (JAX partitionable semantics) ----------------
__host__ __device__ inline uint32_t rotl32(uint32_t x, int d) {
#ifdef __HIP_DEVICE_COMPILE__
    return __builtin_amdgcn_alignbit(x, x, 32 - d);
#else
    return (x << d) | (x >> (32 - d));
#endif
}

__host__ __device__ inline void tf2x32(uint32_t k0, uint32_t k1, uint32_t x0, uint32_t x1,
                                       uint32_t& o0, uint32_t& o1) {
    uint32_t ks2 = k0 ^ k1 ^ 0x1BD11BDAu;
    x0 += k0; x1 += k1;
#define TFR(r) { x0 += x1; x1 = rotl32(x1, r); x1 ^= x0; }
    TFR(13) TFR(15) TFR(26) TFR(6)
    x0 += k1; x1 += ks2 + 1u;
    TFR(17) TFR(29) TFR(16) TFR(24)
    x0 += ks2; x1 += k0 + 2u;
    TFR(13) TFR(15) TFR(26) TFR(6)
    x0 += k0; x1 += k1 + 3u;
    TFR(17) TFR(29) TFR(16) TFR(24)
    x0 += k1; x1 += ks2 + 4u;
    TFR(13) TFR(15) TFR(26) TFR(6)
    x0 += ks2; x1 += k0 + 5u;
#undef TFR
    o0 = x0; o1 = x1;
}

__device__ inline float bf_lo(uint32_t u) { return __uint_as_float(u << 16); }
__device__ inline float bf_hi(uint32_t u) { return __uint_as_float(u & 0xFFFF0000u); }

// keep decision only (index-dependent, NO data dependency — hides load latency)
__device__ inline bool tf_keep(unsigned idx, uint32_t k0, uint32_t k1) {
    uint32_t a, b;
    tf2x32(k0, k1, 0u, idx, a, b);
    return (((a ^ b) >> 9) < 6710887u);  // u < 0.8 exactly
}
__device__ inline uint32_t bfbits(float x) {  // rne bf16 bits (low 16)
    uint32_t u = __float_as_uint(x);
    return ((u + 0x7FFFu + ((u >> 16) & 1u)) >> 16) & 0xFFFFu;
}

__device__ inline short f2bf(float f) {
    uint32_t u = __float_as_uint(f);
    uint32_t r = (u + 0x7FFFu + ((u >> 16) & 1u)) >> 16;
    return (short)r;
}

// region constants (order gg, dd, dt, td)
#define CUM_E0 600000u
#define CUM_E1 720000u
#define CUM_E2 870000u
#define CUM_E3 1020000u

// ---------------- weight transpose/cast body ----------------
struct CastT4P {
    unsigned c0, c1, c2, c3;
    int lgK0, lgK1, lgK2, lgK3;
    int N;
};
__device__ inline void castT_body(unsigned idx, const float* W0, const float* W1,
                                  const float* W2, const float* W3,
                                  short* __restrict__ Wt, const CastT4P& P) {
    if (idx >= P.c3) return;
    unsigned base; const float* W; int lgK;
    if (idx >= P.c2)      { base = P.c2; W = W3; lgK = P.lgK3; }
    else if (idx >= P.c1) { base = P.c1; W = W2; lgK = P.lgK2; }
    else if (idx >= P.c0) { base = P.c0; W = W1; lgK = P.lgK1; }
    else                  { base = 0u;   W = W0; lgK = P.lgK0; }
    unsigned local = idx - base;
    unsigned n = local >> lgK, k = local & ((1u << lgK) - 1u);
    Wt[idx] = f2bf(W[(size_t)k * P.N + n]);
}

// ---------------- CSR count + L0 castT tail ----------------
__global__ __launch_bounds__(256) void count4x_kernel(
    const int* __restrict__ gg, const int* __restrict__ dd,
    const int* __restrict__ dt, const int* __restrict__ td, int* __restrict__ cnt,
    const float* __restrict__ W0, const float* __restrict__ W1,
    const float* __restrict__ W2, const float* __restrict__ W3,
    short* __restrict__ Wt, CastT4P P, int countBlocks) {
    int bx = blockIdx.x;
    if (bx >= countBlocks) {
        castT_body((unsigned)(bx - countBlocks) * 256u + threadIdx.x, W0, W1, W2, W3, Wt, P);
        return;
    }
    unsigned e = (unsigned)bx * 256u + threadIdx.x;
    if (e >= CUM_E3) return;
    const int* dsts; unsigned base, noff;
    if (e >= CUM_E2)      { dsts = td + E_DT; base = CUM_E2; noff = 43000; }
    else if (e >= CUM_E1) { dsts = dt + E_DT; base = CUM_E1; noff = 23000; }
    else if (e >= CUM_E0) { dsts = dd + E_DD; base = CUM_E0; noff = 20000; }
    else                  { dsts = gg + E_GG; base = 0;      noff = 0; }
    atomicAdd(&cnt[noff + dsts[e - base]], 1);
}

// ---------------- parallel scan over cnt[46000] ----------------
__global__ __launch_bounds__(1024) void scan_p1(const int* __restrict__ cnt,
                                                int* __restrict__ tmp, int* __restrict__ bsum) {
    __shared__ int buf[1024];
    int tid = threadIdx.x;
    int i = blockIdx.x * 1024 + tid;
    int v = (i < 46000) ? cnt[i] : 0;
    buf[tid] = v;
    __syncthreads();
    for (int off = 1; off < 1024; off <<= 1) {
        int t = (tid >= off) ? buf[tid - off] : 0;
        __syncthreads();
        buf[tid] += t;
        __syncthreads();
    }
    if (i < 46000) tmp[i] = buf[tid];
    if (tid == 1023) bsum[blockIdx.x] = buf[1023];
}

__global__ void scan_p2(int* __restrict__ bsum) {
    int lane = threadIdx.x;
    int v = (lane < 45) ? bsum[lane] : 0;
    int orig = v;
    for (int off = 1; off < 64; off <<= 1) {
        int t = __shfl_up(v, off, 64);
        if (lane >= off) v += t;
    }
    if (lane < 45) bsum[lane] = v - orig;
}

__global__ __launch_bounds__(1024) void scan_p3(const int* __restrict__ cnt,
                                                const int* __restrict__ tmp,
                                                const int* __restrict__ bsum,
                                                int* __restrict__ rpall, int* __restrict__ pos,
                                                float* __restrict__ dinv_g,
                                                float* __restrict__ dinv_d) {
    int i = blockIdx.x * 1024 + threadIdx.x;
    if (i < 46000) {
        int g = tmp[i] - cnt[i] + bsum[blockIdx.x];
        rpall[i] = g;
        pos[i] = g;
        if (i < 20000) dinv_g[i] = 1.0f / sqrtf((float)cnt[i] + 1.0f);
        else if (i < 23000) dinv_d[i - 20000] = 1.0f / sqrtf((float)cnt[i] + 1.0f);
    }
    if (i == 0) rpall[46000] = (int)CUM_E3;
}

// ---------------- CSR fill ----------------
__global__ __launch_bounds__(256) void fill_kernel(
    const int* __restrict__ gg, const int* __restrict__ dd,
    const int* __restrict__ dt, const int* __restrict__ td,
    int* __restrict__ pos, int* __restrict__ col) {
    unsigned e = blockIdx.x * 256u + threadIdx.x;
    if (e >= CUM_E3) return;
    const int* ei; unsigned base, noff; int E;
    if (e >= CUM_E2)      { ei = td; base = CUM_E2; noff = 43000; E = E_DT; }
    else if (e >= CUM_E1) { ei = dt; base = CUM_E1; noff = 23000; E = E_DT; }
    else if (e >= CUM_E0) { ei = dd; base = CUM_E0; noff = 20000; E = E_DD; }
    else                  { ei = gg; base = 0;      noff = 0;     E = E_GG; }
    unsigned local = e - base;
    int src = ei[local], dst = ei[E + local];
    int p = atomicAdd(&pos[noff + dst], 1);
    col[p] = src;
}

// ---------------- FUSED dropout+GEMM: C = rowscale*1.25 * (dropout(X)bf16 @ Wt^T) ----------
// BM=32, BN=full width, BK=32, 256 threads = 4 waves (wave tile 32 x BN/4).
// r16 post-mortem: bank conflicts were hidden (4.1M->0 changed nothing); the limiter is
// Occupancy 34.5% at VALUBusy 80%. BK=32 halves LDS (18KB L0 / 10KB L1) -> 8 blocks/CU,
// and shrinks staging regs. No swizzle (conflicts proven hidden). Named scalars only.
struct GDescF { const float* X; unsigned boff, coff; const float* rs; int M, K, mb0; uint32_t k0, k1; };
template <int BN>
__global__ __launch_bounds__(256, 2) void gemmf_kernel(
    const short* __restrict__ Wb, short* __restrict__ Cb,
    GDescF d0, GDescF d1, GDescF d2, GDescF d3) {
    constexpr int WN = BN / 4;    // wave N tile: 64 (L0) / 32 (L1)
    constexpr int NF = WN / 16;   // 4 / 2
    constexpr int TPR = 256 / BN; // threads per B row: 1 / 2
    __shared__ short As[32 * 32];
    __shared__ short Bs[BN * 32];
    GDescF d;
    int bx = blockIdx.x;
    if (bx >= d3.mb0) d = d3;
    else if (bx >= d2.mb0) d = d2;
    else if (bx >= d1.mb0) d = d1;
    else d = d0;
    bx -= d.mb0;
    const int M = d.M, K = d.K;
    const short* Bt = Wb + d.boff;
    short* C = Cb + d.coff;
    const uint32_t k0 = d.k0, k1 = d.k1;

    int tid = threadIdx.x;
    int lane = tid & 63, w = tid >> 6;
    int m = lane & 15, kb = lane >> 4;
    int n0w = w * WN;
    int gm = bx * 32;

    // A: thread -> (row ar in [0,32), cols ac..ac+3); threefry index = row*K + col
    int ar = tid >> 3, ac = (tid & 7) * 4;
    int agr = min(gm + ar, M - 1);
    const float* pax = d.X + (size_t)agr * K + ac;
    unsigned abase = (unsigned)agr * (unsigned)K + (unsigned)ac;
    int awslot = ar * 32 + ac;
    // B: thread stages 32/TPR elems of row brow at col bcol
    int brow = tid / TPR;
    int bcol = (tid % TPR) * (32 / TPR);
    const short* pb = Bt + (size_t)brow * K + bcol;
    int bwslot = brow * 32 + bcol;

    f32x4 acc[2][NF];
#pragma unroll
    for (int i = 0; i < 2; i++)
#pragma unroll
        for (int j = 0; j < NF; j++) acc[i][j] = (f32x4){0.f, 0.f, 0.f, 0.f};

    int nt = K >> 5;
    for (int t = 0; t < nt; ++t) {
        int kt = t << 5;
        // issue loads (latency hidden under the threefry chain below)
        float4 xa = *(const float4*)(pax + kt);
        uint4 b0 = *(const uint4*)(pb + kt);
        uint4 b1, b2, b3;
        if constexpr (TPR == 1) {  // full row: 4 uint4
            b1 = *(const uint4*)(pb + kt + 8);
            b2 = *(const uint4*)(pb + kt + 16);
            b3 = *(const uint4*)(pb + kt + 24);
        } else {                   // half row: 2 uint4
            b1 = *(const uint4*)(pb + kt + 8);
        }
        unsigned li = abase + (unsigned)kt;
        bool e0 = tf_keep(li + 0u, k0, k1), e1 = tf_keep(li + 1u, k0, k1);
        bool e2 = tf_keep(li + 2u, k0, k1), e3 = tf_keep(li + 3u, k0, k1);
        uint32_t w0 = (e0 ? bfbits(xa.x) : 0u) | ((e1 ? bfbits(xa.y) : 0u) << 16);
        uint32_t w1 = (e2 ? bfbits(xa.z) : 0u) | ((e3 ? bfbits(xa.w) : 0u) << 16);
        __syncthreads();  // previous tile's MFMA reads done
        *(uint2*)&As[awslot] = make_uint2(w0, w1);
        *(uint4*)&Bs[bwslot] = b0;
        if constexpr (TPR == 1) {
            *(uint4*)&Bs[bwslot + 8] = b1;
            *(uint4*)&Bs[bwslot + 16] = b2;
            *(uint4*)&Bs[bwslot + 24] = b3;
        } else {
            *(uint4*)&Bs[bwslot + 8] = b1;
        }
        __syncthreads();
        {
            bf16x8 a0 = *(const bf16x8*)&As[m * 32 + kb * 8];
            bf16x8 a1 = *(const bf16x8*)&As[(16 + m) * 32 + kb * 8];
#pragma unroll
            for (int nf = 0; nf < NF; nf++) {
                bf16x8 bf = *(const bf16x8*)&Bs[(n0w + nf * 16 + m) * 32 + kb * 8];
                acc[0][nf] = __builtin_amdgcn_mfma_f32_16x16x32_bf16(a0, bf, acc[0][nf], 0, 0, 0);
                acc[1][nf] = __builtin_amdgcn_mfma_f32_16x16x32_bf16(a1, bf, acc[1][nf], 0, 0, 0);
            }
        }
    }
    // C/D layout: col = lane&15, row = kb*4 + j
#pragma unroll
    for (int mf = 0; mf < 2; ++mf)
#pragma unroll
        for (int j = 0; j < 4; ++j) {
            int r = gm + mf * 16 + kb * 4 + j;
            if (r < M) {
                float s = (d.rs ? d.rs[r] : 1.0f) * 1.25f;  // dropout scale folded here
#pragma unroll
                for (int nf = 0; nf < NF; ++nf)
                    C[(size_t)r * BN + n0w + nf * 16 + m] = f2bf(acc[mf][nf][j] * s);
            }
        }
}

// ---------------- fused dual aggregate (gene+drug one dispatch, optional castT tail) ----
struct AggP {
    const short* XWa; const int* rpa; const float* dinv; const float* ba;
    const short* XWb; const int* rpb; const float* bb;
    float* out; int n_dst;
};

template <int F>
__device__ inline void agg_body(const AggP& P, const int* __restrict__ col, int row, int lane) {
    const int h = 64 * F;
    int c0 = lane * F;
    float acc[F], va[F];

#pragma unroll
    for (int i = 0; i < F; i++) acc[i] = 0.f;
    {
        if constexpr (F == 4) {
            uint2 u = *(const uint2*)(P.XWa + (size_t)row * h + c0);
            acc[0] += bf_lo(u.x); acc[1] += bf_hi(u.x);
            acc[2] += bf_lo(u.y); acc[3] += bf_hi(u.y);
        } else {
            uint32_t u = *(const uint32_t*)(P.XWa + (size_t)row * h + c0);
            acc[0] += bf_lo(u); acc[1] += bf_hi(u);
        }
        int s0 = P.rpa[row], s1 = P.rpa[row + 1];
        int p = s0;
        for (; p + 8 <= s1; p += 8) {
            int c[8];
#pragma unroll
            for (int i = 0; i < 8; i++) c[i] = col[p + i];
            if constexpr (F == 4) {
                uint2 g[8];
#pragma unroll
                for (int i = 0; i < 8; i++) g[i] = *(const uint2*)(P.XWa + (size_t)c[i] * h + c0);
#pragma unroll
                for (int i = 0; i < 8; i++) {
                    acc[0] += bf_lo(g[i].x); acc[1] += bf_hi(g[i].x);
                    acc[2] += bf_lo(g[i].y); acc[3] += bf_hi(g[i].y);
                }
            } else {
                uint32_t g[8];
#pragma unroll
                for (int i = 0; i < 8; i++) g[i] = *(const uint32_t*)(P.XWa + (size_t)c[i] * h + c0);
#pragma unroll
                for (int i = 0; i < 8; i++) { acc[0] += bf_lo(g[i]); acc[1] += bf_hi(g[i]); }
            }
        }
        for (; p < s1; p++) {
            int s = col[p];
            if constexpr (F == 4) {
                uint2 u = *(const uint2*)(P.XWa + (size_t)s * h + c0);
                acc[0] += bf_lo(u.x); acc[1] += bf_hi(u.x);
                acc[2] += bf_lo(u.y); acc[3] += bf_hi(u.y);
            } else {
                uint32_t u = *(const uint32_t*)(P.XWa + (size_t)s * h + c0);
                acc[0] += bf_lo(u); acc[1] += bf_hi(u);
            }
        }
    }
    float mul = P.dinv[row];
    float ssa = 0.f;
#pragma unroll
    for (int i = 0; i < F; i++) {
        float v = fmaxf(acc[i] * mul + P.ba[c0 + i], 0.f);
        va[i] = v;
        ssa += v * v;
    }

#pragma unroll
    for (int i = 0; i < F; i++) acc[i] = 0.f;
    {
        int s0 = P.rpb[row], s1 = P.rpb[row + 1];
        int p = s0;
        for (; p + 8 <= s1; p += 8) {
            int c[8];
#pragma unroll
            for (int i = 0; i < 8; i++) c[i] = col[p + i];
            if constexpr (F == 4) {
                uint2 g[8];
#pragma unroll
                for (int i = 0; i < 8; i++) g[i] = *(const uint2*)(P.XWb + (size_t)c[i] * h + c0);
#pragma unroll
                for (int i = 0; i < 8; i++) {
                    acc[0] += bf_lo(g[i].x); acc[1] += bf_hi(g[i].x);
                    acc[2] += bf_lo(g[i].y); acc[3] += bf_hi(g[i].y);
                }
            } else {
                uint32_t g[8];
#pragma unroll
                for (int i = 0; i < 8; i++) g[i] = *(const uint32_t*)(P.XWb + (size_t)c[i] * h + c0);
#pragma unroll
                for (int i = 0; i < 8; i++) { acc[0] += bf_lo(g[i]); acc[1] += bf_hi(g[i]); }
            }
        }
        for (; p < s1; p++) {
            int s = col[p];
            if constexpr (F == 4) {
                uint2 u = *(const uint2*)(P.XWb + (size_t)s * h + c0);
                acc[0] += bf_lo(u.x); acc[1] += bf_hi(u.x);
                acc[2] += bf_lo(u.y); acc[3] += bf_hi(u.y);
            } else {
                uint32_t u = *(const uint32_t*)(P.XWb + (size_t)s * h + c0);
                acc[0] += bf_lo(u); acc[1] += bf_hi(u);
            }
        }
    }
    float ssb = 0.f;
#pragma unroll
    for (int i = 0; i < F; i++) {
        float v = fmaxf(acc[i] + P.bb[c0 + i], 0.f);
        acc[i] = v;
        ssb += v * v;
    }

#pragma unroll
    for (int off = 32; off >= 1; off >>= 1) {
        ssa += __shfl_xor(ssa, off, 64);
        ssb += __shfl_xor(ssb, off, 64);
    }
    float sa = 1.0f / fmaxf(sqrtf(ssa), 1e-12f);
    float sb = 1.0f / fmaxf(sqrtf(ssb), 1e-12f);
    float* orow = P.out + (size_t)row * h + c0;
    if constexpr (F == 4) {
        *(float4*)orow = make_float4(va[0] * sa + acc[0] * sb, va[1] * sa + acc[1] * sb,
                                     va[2] * sa + acc[2] * sb, va[3] * sa + acc[3] * sb);
    } else {
        *(float2*)orow = make_float2(va[0] * sa + acc[0] * sb, va[1] * sa + acc[1] * sb);
    }
}

template <int F, bool TAIL>
__global__ __launch_bounds__(256) void agg2x_kernel(
    AggP pg, AggP pd, const int* __restrict__ col, int geneBlocks, int aggBlocks,
    const float* W0, const float* W1, const float* W2, const float* W3,
    short* Wt, CastT4P tp) {
    int bx = blockIdx.x;
    if (TAIL && bx >= aggBlocks) {
        castT_body((unsigned)(bx - aggBlocks) * 256u + threadIdx.x, W0, W1, W2, W3, Wt, tp);
        return;
    }
    int lane = threadIdx.x & 63;
    if (bx < geneBlocks) {
        int row = bx * 4 + (threadIdx.x >> 6);
        if (row < pg.n_dst) agg_body<F>(pg, col, row, lane);
    } else {
        int row = (bx - geneBlocks) * 4 + (threadIdx.x >> 6);
        if (row < pd.n_dst) agg_body<F>(pd, col, row, lane);
    }
}

// ---------------- host ----------------
extern "C" void kernel_launch(void* const* d_in, const int* in_sizes, int n_in,
                              void* d_out, int out_size, void* d_ws, size_t ws_size,
                              hipStream_t stream) {
    const float* gene = (const float*)d_in[0];
    const float* drug = (const float*)d_in[1];
    const int* ei_gg = (const int*)d_in[2];
    const int* ei_dd = (const int*)d_in[3];
    const int* ei_dt = (const int*)d_in[4];
    const int* ei_td = (const int*)d_in[5];
    const float* W0gg = (const float*)d_in[6];  const float* b0gg = (const float*)d_in[7];
    const float* W0dd = (const float*)d_in[8];  const float* b0dd = (const float*)d_in[9];
    const float* W0dt = (const float*)d_in[10]; const float* b0dt = (const float*)d_in[11];
    const float* W0td = (const float*)d_in[12]; const float* b0td = (const float*)d_in[13];
    const float* W1gg = (const float*)d_in[14]; const float* b1gg = (const float*)d_in[15];
    const float* W1dd = (const float*)d_in[16]; const float* b1dd = (const float*)d_in[17];
    const float* W1dt = (const float*)d_in[18]; const float* b1dt = (const float*)d_in[19];
    const float* W1td = (const float*)d_in[20]; const float* b1td = (const float*)d_in[21];

    uint32_t dk[8][2];
    for (uint32_t i = 0; i < 8; i++) tf2x32(0u, 42u, 0u, i, dk[i][0], dk[i][1]);

    char* p = (char*)d_ws;
    auto take = [&](size_t bytes) -> void* {
        void* r = (void*)p;
        p += (bytes + 255) & ~(size_t)255;
        return r;
    };
    short* XW   = (short*)take(sizeof(short) * 11776000ULL);
    short* Wt0  = (short*)take(sizeof(short) * 786432ULL);
    short* Wt1  = (short*)take(sizeof(short) * 131072ULL);
    float* xg1  = (float*)take(sizeof(float) * (size_t)N_GENE * H0);
    float* xd1  = (float*)take(sizeof(float) * (size_t)N_DRUG * H0);
    float* dinv_g = (float*)take(sizeof(float) * N_GENE);
    float* dinv_d = (float*)take(sizeof(float) * N_DRUG);
    int* cnt   = (int*)take(4 * 46000);
    int* tmp   = (int*)take(4 * 46000);
    int* bsum  = (int*)take(4 * 64);
    int* pos   = (int*)take(4 * 46000);
    int* rpall = (int*)take(4 * 46001);
    int* col   = (int*)take(4 * 1020000);

    const int* rp_gg = rpall;
    const int* rp_dd = rpall + 20000;
    const int* rp_dt = rpall + 23000;
    const int* rp_td = rpall + 43000;

    // ---- CSR build + L0 weight cast ----
    hipMemsetAsync(cnt, 0, 4 * 46000, stream);
    CastT4P tp0 = {262144u, 524288u, 655360u, 786432u, 10, 10, 9, 9, H0};
    int countBlocks = (1020000 + 255) / 256;
    count4x_kernel<<<countBlocks + (786432 + 255) / 256, 256, 0, stream>>>(
        ei_gg, ei_dd, ei_dt, ei_td, cnt, W0gg, W0td, W0dd, W0dt, Wt0, tp0, countBlocks);
    scan_p1<<<45, 1024, 0, stream>>>(cnt, tmp, bsum);
    scan_p2<<<1, 64, 0, stream>>>(bsum);
    scan_p3<<<45, 1024, 0, stream>>>(cnt, tmp, bsum, rpall, pos, dinv_g, dinv_d);
    fill_kernel<<<(1020000 + 255) / 256, 256, 0, stream>>>(ei_gg, ei_dd, ei_dt, ei_td, pos, col);

    // block ranges (BM=32): gg 625, td 625, dd 94, dt 94 -> 1438 blocks
    // ================= layer 0 (fused dropout GEMM, BN=256, BK=32) =================
    {
        GDescF g0 = {gene, 0u,      0u,        dinv_g,  N_GENE, 1024, 0,    dk[0][0], dk[0][1]};
        GDescF g1 = {gene, 262144u, 5120000u,  nullptr, N_GENE, 1024, 625,  dk[3][0], dk[3][1]};
        GDescF g2 = {drug, 524288u, 10240000u, dinv_d,  N_DRUG, 512,  1250, dk[1][0], dk[1][1]};
        GDescF g3 = {drug, 655360u, 11008000u, nullptr, N_DRUG, 512,  1344, dk[2][0], dk[2][1]};
        gemmf_kernel<256><<<1438, 256, 0, stream>>>(Wt0, XW, g0, g1, g2, g3);

        AggP pg = {XW, rp_gg, dinv_g, b0gg, XW + 11008000, rp_dt, b0dt, xg1, N_GENE};
        AggP pd = {XW + 10240000, rp_dd, dinv_d, b0dd, XW + 5120000, rp_td, b0td, xd1, N_DRUG};
        CastT4P tp1 = {32768u, 65536u, 98304u, 131072u, 8, 8, 8, 8, H1};
        int geneBlocks = (N_GENE + 3) / 4, aggBlocks = geneBlocks + (N_DRUG + 3) / 4;
        agg2x_kernel<4, true><<<aggBlocks + (131072 + 255) / 256, 256, 0, stream>>>(
            pg, pd, col, geneBlocks, aggBlocks, W1gg, W1td, W1dd, W1dt, Wt1, tp1);
    }

    // ================= layer 1 (fused dropout GEMM, BN=128, BK=32) =================
    {
        GDescF g0 = {xg1, 0u,     0u,        dinv_g,  N_GENE, 256, 0,    dk[4][0], dk[4][1]};
        GDescF g1 = {xg1, 32768u, 5120000u,  nullptr, N_GENE, 256, 625,  dk[7][0], dk[7][1]};
        GDescF g2 = {xd1, 65536u, 10240000u, dinv_d,  N_DRUG, 256, 1250, dk[5][0], dk[5][1]};
        GDescF g3 = {xd1, 98304u, 11008000u, nullptr, N_DRUG, 256, 1344, dk[6][0], dk[6][1]};
        gemmf_kernel<128><<<1438, 256, 0, stream>>>(Wt1, XW, g0, g1, g2, g3);

        float* og = (float*)d_out;
        float* od = og + (size_t)N_GENE * H1;
        AggP pg = {XW, rp_gg, dinv_g, b1gg, XW + 11008000, rp_dt, b1dt, og, N_GENE};
        AggP pd = {XW + 10240000, rp_dd, dinv_d, b1dd, XW + 5120000, rp_td, b1td, od, N_DRUG};
        CastT4P tpDummy = {0u, 0u, 0u, 0u, 0, 0, 0, 0, 0};
        int geneBlocks = (N_GENE + 3) / 4, aggBlocks = geneBlocks + (N_DRUG + 3) / 4;
        agg2x_kernel<2, false><<<aggBlocks, 256, 0, stream>>>(
            pg, pd, col, geneBlocks, aggBlocks,
            nullptr, nullptr, nullptr, nullptr, nullptr, tpDummy);
    }
}

// Round 18
// 400.861 us; speedup vs baseline: 1.0347x; 1.0347x over previous
//
#include <hip/hip_runtime.h>
#include <stdint.h>

#define N_GENE 20000
#define N_DRUG 3000
#define D_GENE 1024
#define D_DRUG 512
#define H0 256
#define H1 128
#define E_GG 600000
#define E_DD 120000
#define E_DT 150000

typedef __attribute__((ext_vector_type(8))) short bf16x8;
typedef __attribute__((ext_vector_type(4))) float f32x4;

// ---------------- Threefry-2x32 (JAX partitionable semantics) ----------------
__host__ __device__ inline uint32_t rotl32(uint32_t x, int d) {
#ifdef __HIP_DEVICE_COMPILE__
    return __builtin_amdgcn_alignbit(x, x, 32 - d);
#else
    return (x << d) | (x >> (32 - d));
#endif
}

__host__ __device__ inline void tf2x32(uint32_t k0, uint32_t k1, uint32_t x0, uint32_t x1,
                                       uint32_t& o0, uint32_t& o1) {
    uint32_t ks2 = k0 ^ k1 ^ 0x1BD11BDAu;
    x0 += k0; x1 += k1;
#define TFR(r) { x0 += x1; x1 = rotl32(x1, r); x1 ^= x0; }
    TFR(13) TFR(15) TFR(26) TFR(6)
    x0 += k1; x1 += ks2 + 1u;
    TFR(17) TFR(29) TFR(16) TFR(24)
    x0 += ks2; x1 += k0 + 2u;
    TFR(13) TFR(15) TFR(26) TFR(6)
    x0 += k0; x1 += k1 + 3u;
    TFR(17) TFR(29) TFR(16) TFR(24)
    x0 += k1; x1 += ks2 + 4u;
    TFR(13) TFR(15) TFR(26) TFR(6)
    x0 += ks2; x1 += k0 + 5u;
#undef TFR
    o0 = x0; o1 = x1;
}

__device__ inline float bf_lo(uint32_t u) { return __uint_as_float(u << 16); }
__device__ inline float bf_hi(uint32_t u) { return __uint_as_float(u & 0xFFFF0000u); }

// keep decision only (index-dependent, NO data dependency — hides load latency)
__device__ inline bool tf_keep(unsigned idx, uint32_t k0, uint32_t k1) {
    uint32_t a, b;
    tf2x32(k0, k1, 0u, idx, a, b);
    return (((a ^ b) >> 9) < 6710887u);  // u < 0.8 exactly
}
__device__ inline uint32_t bfbits(float x) {  // rne bf16 bits (low 16)
    uint32_t u = __float_as_uint(x);
    return ((u + 0x7FFFu + ((u >> 16) & 1u)) >> 16) & 0xFFFFu;
}

__device__ inline short f2bf(float f) {
    uint32_t u = __float_as_uint(f);
    uint32_t r = (u + 0x7FFFu + ((u >> 16) & 1u)) >> 16;
    return (short)r;
}

// region constants (order gg, dd, dt, td)
#define CUM_E0 600000u
#define CUM_E1 720000u
#define CUM_E2 870000u
#define CUM_E3 1020000u

// ---------------- weight transpose/cast body ----------------
struct CastT4P {
    unsigned c0, c1, c2, c3;
    int lgK0, lgK1, lgK2, lgK3;
    int N;
};
__device__ inline void castT_body(unsigned idx, const float* W0, const float* W1,
                                  const float* W2, const float* W3,
                                  short* __restrict__ Wt, const CastT4P& P) {
    if (idx >= P.c3) return;
    unsigned base; const float* W; int lgK;
    if (idx >= P.c2)      { base = P.c2; W = W3; lgK = P.lgK3; }
    else if (idx >= P.c1) { base = P.c1; W = W2; lgK = P.lgK2; }
    else if (idx >= P.c0) { base = P.c0; W = W1; lgK = P.lgK1; }
    else                  { base = 0u;   W = W0; lgK = P.lgK0; }
    unsigned local = idx - base;
    unsigned n = local >> lgK, k = local & ((1u << lgK) - 1u);
    Wt[idx] = f2bf(W[(size_t)k * P.N + n]);
}

// ---------------- CSR count + L0 castT tail ----------------
__global__ __launch_bounds__(256) void count4x_kernel(
    const int* __restrict__ gg, const int* __restrict__ dd,
    const int* __restrict__ dt, const int* __restrict__ td, int* __restrict__ cnt,
    const float* __restrict__ W0, const float* __restrict__ W1,
    const float* __restrict__ W2, const float* __restrict__ W3,
    short* __restrict__ Wt, CastT4P P, int countBlocks) {
    int bx = blockIdx.x;
    if (bx >= countBlocks) {
        castT_body((unsigned)(bx - countBlocks) * 256u + threadIdx.x, W0, W1, W2, W3, Wt, P);
        return;
    }
    unsigned e = (unsigned)bx * 256u + threadIdx.x;
    if (e >= CUM_E3) return;
    const int* dsts; unsigned base, noff;
    if (e >= CUM_E2)      { dsts = td + E_DT; base = CUM_E2; noff = 43000; }
    else if (e >= CUM_E1) { dsts = dt + E_DT; base = CUM_E1; noff = 23000; }
    else if (e >= CUM_E0) { dsts = dd + E_DD; base = CUM_E0; noff = 20000; }
    else                  { dsts = gg + E_GG; base = 0;      noff = 0; }
    atomicAdd(&cnt[noff + dsts[e - base]], 1);
}

// ---------------- parallel scan over cnt[46000] ----------------
__global__ __launch_bounds__(1024) void scan_p1(const int* __restrict__ cnt,
                                                int* __restrict__ tmp, int* __restrict__ bsum) {
    __shared__ int buf[1024];
    int tid = threadIdx.x;
    int i = blockIdx.x * 1024 + tid;
    int v = (i < 46000) ? cnt[i] : 0;
    buf[tid] = v;
    __syncthreads();
    for (int off = 1; off < 1024; off <<= 1) {
        int t = (tid >= off) ? buf[tid - off] : 0;
        __syncthreads();
        buf[tid] += t;
        __syncthreads();
    }
    if (i < 46000) tmp[i] = buf[tid];
    if (tid == 1023) bsum[blockIdx.x] = buf[1023];
}

__global__ void scan_p2(int* __restrict__ bsum) {
    int lane = threadIdx.x;
    int v = (lane < 45) ? bsum[lane] : 0;
    int orig = v;
    for (int off = 1; off < 64; off <<= 1) {
        int t = __shfl_up(v, off, 64);
        if (lane >= off) v += t;
    }
    if (lane < 45) bsum[lane] = v - orig;
}

__global__ __launch_bounds__(1024) void scan_p3(const int* __restrict__ cnt,
                                                const int* __restrict__ tmp,
                                                const int* __restrict__ bsum,
                                                int* __restrict__ rpall, int* __restrict__ pos,
                                                float* __restrict__ dinv_g,
                                                float* __restrict__ dinv_d) {
    int i = blockIdx.x * 1024 + threadIdx.x;
    if (i < 46000) {
        int g = tmp[i] - cnt[i] + bsum[blockIdx.x];
        rpall[i] = g;
        pos[i] = g;
        if (i < 20000) dinv_g[i] = 1.0f / sqrtf((float)cnt[i] + 1.0f);
        else if (i < 23000) dinv_d[i - 20000] = 1.0f / sqrtf((float)cnt[i] + 1.0f);
    }
    if (i == 0) rpall[46000] = (int)CUM_E3;
}

// ---------------- CSR fill ----------------
__global__ __launch_bounds__(256) void fill_kernel(
    const int* __restrict__ gg, const int* __restrict__ dd,
    const int* __restrict__ dt, const int* __restrict__ td,
    int* __restrict__ pos, int* __restrict__ col) {
    unsigned e = blockIdx.x * 256u + threadIdx.x;
    if (e >= CUM_E3) return;
    const int* ei; unsigned base, noff; int E;
    if (e >= CUM_E2)      { ei = td; base = CUM_E2; noff = 43000; E = E_DT; }
    else if (e >= CUM_E1) { ei = dt; base = CUM_E1; noff = 23000; E = E_DT; }
    else if (e >= CUM_E0) { ei = dd; base = CUM_E0; noff = 20000; E = E_DD; }
    else                  { ei = gg; base = 0;      noff = 0;     E = E_GG; }
    unsigned local = e - base;
    int src = ei[local], dst = ei[E + local];
    int p = atomicAdd(&pos[noff + dst], 1);
    col[p] = src;
}

// ---------------- FUSED dropout+GEMM: C = rowscale*1.25 * (dropout(X)bf16 @ Wt^T) ----------
// BM=32, BN=full width, BK=64, 256 threads = 4 waves (wave tile 32 x BN/4).
// r16 configuration — the measured optimum of the explored space:
//   r14 BK=64 padded (4.1M conflicts): 148us | r15 B-direct: 165us |
//   r16 BK=64 swizzled (0 conflicts): 147us | r17 BK=32 (20.6M conflicts): 161us
// UNPADDED [row][64] tiles, 16B granule g' = g ^ (row&7). Named scalars only (rule #20).
struct GDescF { const float* X; unsigned boff, coff; const float* rs; int M, K, mb0; uint32_t k0, k1; };
template <int BN>
__global__ __launch_bounds__(256, 2) void gemmf_kernel(
    const short* __restrict__ Wb, short* __restrict__ Cb,
    GDescF d0, GDescF d1, GDescF d2, GDescF d3) {
    constexpr int WN = BN / 4;   // wave N tile: 64 (L0) / 32 (L1)
    constexpr int NF = WN / 16;  // 4 / 2
    constexpr int SB = BN / 32;  // B uint4/thread: 8 / 4
    __shared__ short As[32 * 64];
    __shared__ short Bs[BN * 64];
    GDescF d;
    int bx = blockIdx.x;
    if (bx >= d3.mb0) d = d3;
    else if (bx >= d2.mb0) d = d2;
    else if (bx >= d1.mb0) d = d1;
    else d = d0;
    bx -= d.mb0;
    const int M = d.M, K = d.K;
    const short* Bt = Wb + d.boff;
    short* C = Cb + d.coff;
    const uint32_t k0 = d.k0, k1 = d.k1;

    int tid = threadIdx.x;
    int lane = tid & 63, w = tid >> 6;
    int m = lane & 15, kb = lane >> 4;
    int n0w = w * WN;
    int gm = bx * 32;

    // A: thread -> (row ar in [0,32), granule gr in [0,8)); threefry index = row*K + col
    int ar = tid >> 3, gr = tid & 7;
    int sgw = gr ^ (ar & 7);           // swizzled write granule (same for As and Bs rows)
    int agr = min(gm + ar, M - 1);
    const float* pax = d.X + (size_t)agr * K + gr * 8;
    unsigned abase = (unsigned)agr * (unsigned)K + (unsigned)(gr * 8);
    int awslot = ar * 64 + sgw * 8;
    // B staging: rows ar + 32*i, same granule
    const short* pb = Bt + (size_t)ar * K + gr * 8;
    const size_t bstep = (size_t)32 * K;

    f32x4 acc[2][NF];
#pragma unroll
    for (int i = 0; i < 2; i++)
#pragma unroll
        for (int j = 0; j < NF; j++) acc[i][j] = (f32x4){0.f, 0.f, 0.f, 0.f};

    int nt = K >> 6;
    for (int t = 0; t < nt; ++t) {
        int kt = t << 6;
        // issue loads (latency hidden under the threefry chain below)
        float4 xa = *(const float4*)(pax + kt);
        float4 xb = *(const float4*)(pax + kt + 4);
        uint4 b0 = *(const uint4*)(pb + kt);
        uint4 b1 = *(const uint4*)(pb + kt + bstep);
        uint4 b2 = *(const uint4*)(pb + kt + 2 * bstep);
        uint4 b3 = *(const uint4*)(pb + kt + 3 * bstep);
        uint4 b4, b5, b6, b7;
        if constexpr (SB == 8) {
            b4 = *(const uint4*)(pb + kt + 4 * bstep);
            b5 = *(const uint4*)(pb + kt + 5 * bstep);
            b6 = *(const uint4*)(pb + kt + 6 * bstep);
            b7 = *(const uint4*)(pb + kt + 7 * bstep);
        }
        unsigned li = abase + (unsigned)kt;
        bool e0 = tf_keep(li + 0u, k0, k1), e1 = tf_keep(li + 1u, k0, k1);
        bool e2 = tf_keep(li + 2u, k0, k1), e3 = tf_keep(li + 3u, k0, k1);
        bool e4 = tf_keep(li + 4u, k0, k1), e5 = tf_keep(li + 5u, k0, k1);
        bool e6 = tf_keep(li + 6u, k0, k1), e7 = tf_keep(li + 7u, k0, k1);
        uint32_t w0 = (e0 ? bfbits(xa.x) : 0u) | ((e1 ? bfbits(xa.y) : 0u) << 16);
        uint32_t w1 = (e2 ? bfbits(xa.z) : 0u) | ((e3 ? bfbits(xa.w) : 0u) << 16);
        uint32_t w2 = (e4 ? bfbits(xb.x) : 0u) | ((e5 ? bfbits(xb.y) : 0u) << 16);
        uint32_t w3 = (e6 ? bfbits(xb.z) : 0u) | ((e7 ? bfbits(xb.w) : 0u) << 16);
        __syncthreads();  // previous tile's MFMA reads done
        *(uint4*)&As[awslot] = make_uint4(w0, w1, w2, w3);
        *(uint4*)&Bs[awslot] = b0;
        *(uint4*)&Bs[awslot + 32 * 64] = b1;
        *(uint4*)&Bs[awslot + 64 * 64] = b2;
        *(uint4*)&Bs[awslot + 96 * 64] = b3;
        if constexpr (SB == 8) {
            *(uint4*)&Bs[awslot + 128 * 64] = b4;
            *(uint4*)&Bs[awslot + 160 * 64] = b5;
            *(uint4*)&Bs[awslot + 192 * 64] = b6;
            *(uint4*)&Bs[awslot + 224 * 64] = b7;
        }
        __syncthreads();
#pragma unroll
        for (int ks = 0; ks < 2; ++ks) {
            int sg = ((ks * 4 + kb) ^ (m & 7)) * 8;  // swizzled read granule
            bf16x8 a0 = *(const bf16x8*)&As[m * 64 + sg];
            bf16x8 a1 = *(const bf16x8*)&As[(16 + m) * 64 + sg];
#pragma unroll
            for (int nf = 0; nf < NF; nf++) {
                bf16x8 bf = *(const bf16x8*)&Bs[(n0w + nf * 16 + m) * 64 + sg];
                acc[0][nf] = __builtin_amdgcn_mfma_f32_16x16x32_bf16(a0, bf, acc[0][nf], 0, 0, 0);
                acc[1][nf] = __builtin_amdgcn_mfma_f32_16x16x32_bf16(a1, bf, acc[1][nf], 0, 0, 0);
            }
        }
    }
    // C/D layout: col = lane&15, row = kb*4 + j
#pragma unroll
    for (int mf = 0; mf < 2; ++mf)
#pragma unroll
        for (int j = 0; j < 4; ++j) {
            int r = gm + mf * 16 + kb * 4 + j;
            if (r < M) {
                float s = (d.rs ? d.rs[r] : 1.0f) * 1.25f;  // dropout scale folded here
#pragma unroll
                for (int nf = 0; nf < NF; ++nf)
                    C[(size_t)r * BN + n0w + nf * 16 + m] = f2bf(acc[mf][nf][j] * s);
            }
        }
}

// ---------------- fused dual aggregate (gene+drug one dispatch, optional castT tail) ----
struct AggP {
    const short* XWa; const int* rpa; const float* dinv; const float* ba;
    const short* XWb; const int* rpb; const float* bb;
    float* out; int n_dst;
};

template <int F>
__device__ inline void agg_body(const AggP& P, const int* __restrict__ col, int row, int lane) {
    const int h = 64 * F;
    int c0 = lane * F;
    float acc[F], va[F];

#pragma unroll
    for (int i = 0; i < F; i++) acc[i] = 0.f;
    {
        if constexpr (F == 4) {
            uint2 u = *(const uint2*)(P.XWa + (size_t)row * h + c0);
            acc[0] += bf_lo(u.x); acc[1] += bf_hi(u.x);
            acc[2] += bf_lo(u.y); acc[3] += bf_hi(u.y);
        } else {
            uint32_t u = *(const uint32_t*)(P.XWa + (size_t)row * h + c0);
            acc[0] += bf_lo(u); acc[1] += bf_hi(u);
        }
        int s0 = P.rpa[row], s1 = P.rpa[row + 1];
        int p = s0;
        for (; p + 8 <= s1; p += 8) {
            int c[8];
#pragma unroll
            for (int i = 0; i < 8; i++) c[i] = col[p + i];
            if constexpr (F == 4) {
                uint2 g[8];
#pragma unroll
                for (int i = 0; i < 8; i++) g[i] = *(const uint2*)(P.XWa + (size_t)c[i] * h + c0);
#pragma unroll
                for (int i = 0; i < 8; i++) {
                    acc[0] += bf_lo(g[i].x); acc[1] += bf_hi(g[i].x);
                    acc[2] += bf_lo(g[i].y); acc[3] += bf_hi(g[i].y);
                }
            } else {
                uint32_t g[8];
#pragma unroll
                for (int i = 0; i < 8; i++) g[i] = *(const uint32_t*)(P.XWa + (size_t)c[i] * h + c0);
#pragma unroll
                for (int i = 0; i < 8; i++) { acc[0] += bf_lo(g[i]); acc[1] += bf_hi(g[i]); }
            }
        }
        for (; p < s1; p++) {
            int s = col[p];
            if constexpr (F == 4) {
                uint2 u = *(const uint2*)(P.XWa + (size_t)s * h + c0);
                acc[0] += bf_lo(u.x); acc[1] += bf_hi(u.x);
                acc[2] += bf_lo(u.y); acc[3] += bf_hi(u.y);
            } else {
                uint32_t u = *(const uint32_t*)(P.XWa + (size_t)s * h + c0);
                acc[0] += bf_lo(u); acc[1] += bf_hi(u);
            }
        }
    }
    float mul = P.dinv[row];
    float ssa = 0.f;
#pragma unroll
    for (int i = 0; i < F; i++) {
        float v = fmaxf(acc[i] * mul + P.ba[c0 + i], 0.f);
        va[i] = v;
        ssa += v * v;
    }

#pragma unroll
    for (int i = 0; i < F; i++) acc[i] = 0.f;
    {
        int s0 = P.rpb[row], s1 = P.rpb[row + 1];
        int p = s0;
        for (; p + 8 <= s1; p += 8) {
            int c[8];
#pragma unroll
            for (int i = 0; i < 8; i++) c[i] = col[p + i];
            if constexpr (F == 4) {
                uint2 g[8];
#pragma unroll
                for (int i = 0; i < 8; i++) g[i] = *(const uint2*)(P.XWb + (size_t)c[i] * h + c0);
#pragma unroll
                for (int i = 0; i < 8; i++) {
                    acc[0] += bf_lo(g[i].x); acc[1] += bf_hi(g[i].x);
                    acc[2] += bf_lo(g[i].y); acc[3] += bf_hi(g[i].y);
                }
            } else {
                uint32_t g[8];
#pragma unroll
                for (int i = 0; i < 8; i++) g[i] = *(const uint32_t*)(P.XWb + (size_t)c[i] * h + c0);
#pragma unroll
                for (int i = 0; i < 8; i++) { acc[0] += bf_lo(g[i]); acc[1] += bf_hi(g[i]); }
            }
        }
        for (; p < s1; p++) {
            int s = col[p];
            if constexpr (F == 4) {
                uint2 u = *(const uint2*)(P.XWb + (size_t)s * h + c0);
                acc[0] += bf_lo(u.x); acc[1] += bf_hi(u.x);
                acc[2] += bf_lo(u.y); acc[3] += bf_hi(u.y);
            } else {
                uint32_t u = *(const uint32_t*)(P.XWb + (size_t)s * h + c0);
                acc[0] += bf_lo(u); acc[1] += bf_hi(u);
            }
        }
    }
    float ssb = 0.f;
#pragma unroll
    for (int i = 0; i < F; i++) {
        float v = fmaxf(acc[i] + P.bb[c0 + i], 0.f);
        acc[i] = v;
        ssb += v * v;
    }

#pragma unroll
    for (int off = 32; off >= 1; off >>= 1) {
        ssa += __shfl_xor(ssa, off, 64);
        ssb += __shfl_xor(ssb, off, 64);
    }
    float sa = 1.0f / fmaxf(sqrtf(ssa), 1e-12f);
    float sb = 1.0f / fmaxf(sqrtf(ssb), 1e-12f);
    float* orow = P.out + (size_t)row * h + c0;
    if constexpr (F == 4) {
        *(float4*)orow = make_float4(va[0] * sa + acc[0] * sb, va[1] * sa + acc[1] * sb,
                                     va[2] * sa + acc[2] * sb, va[3] * sa + acc[3] * sb);
    } else {
        *(float2*)orow = make_float2(va[0] * sa + acc[0] * sb, va[1] * sa + acc[1] * sb);
    }
}

template <int F, bool TAIL>
__global__ __launch_bounds__(256) void agg2x_kernel(
    AggP pg, AggP pd, const int* __restrict__ col, int geneBlocks, int aggBlocks,
    const float* W0, const float* W1, const float* W2, const float* W3,
    short* Wt, CastT4P tp) {
    int bx = blockIdx.x;
    if (TAIL && bx >= aggBlocks) {
        castT_body((unsigned)(bx - aggBlocks) * 256u + threadIdx.x, W0, W1, W2, W3, Wt, tp);
        return;
    }
    int lane = threadIdx.x & 63;
    if (bx < geneBlocks) {
        int row = bx * 4 + (threadIdx.x >> 6);
        if (row < pg.n_dst) agg_body<F>(pg, col, row, lane);
    } else {
        int row = (bx - geneBlocks) * 4 + (threadIdx.x >> 6);
        if (row < pd.n_dst) agg_body<F>(pd, col, row, lane);
    }
}

// ---------------- host ----------------
extern "C" void kernel_launch(void* const* d_in, const int* in_sizes, int n_in,
                              void* d_out, int out_size, void* d_ws, size_t ws_size,
                              hipStream_t stream) {
    const float* gene = (const float*)d_in[0];
    const float* drug = (const float*)d_in[1];
    const int* ei_gg = (const int*)d_in[2];
    const int* ei_dd = (const int*)d_in[3];
    const int* ei_dt = (const int*)d_in[4];
    const int* ei_td = (const int*)d_in[5];
    const float* W0gg = (const float*)d_in[6];  const float* b0gg = (const float*)d_in[7];
    const float* W0dd = (const float*)d_in[8];  const float* b0dd = (const float*)d_in[9];
    const float* W0dt = (const float*)d_in[10]; const float* b0dt = (const float*)d_in[11];
    const float* W0td = (const float*)d_in[12]; const float* b0td = (const float*)d_in[13];
    const float* W1gg = (const float*)d_in[14]; const float* b1gg = (const float*)d_in[15];
    const float* W1dd = (const float*)d_in[16]; const float* b1dd = (const float*)d_in[17];
    const float* W1dt = (const float*)d_in[18]; const float* b1dt = (const float*)d_in[19];
    const float* W1td = (const float*)d_in[20]; const float* b1td = (const float*)d_in[21];

    uint32_t dk[8][2];
    for (uint32_t i = 0; i < 8; i++) tf2x32(0u, 42u, 0u, i, dk[i][0], dk[i][1]);

    char* p = (char*)d_ws;
    auto take = [&](size_t bytes) -> void* {
        void* r = (void*)p;
        p += (bytes + 255) & ~(size_t)255;
        return r;
    };
    short* XW   = (short*)take(sizeof(short) * 11776000ULL);
    short* Wt0  = (short*)take(sizeof(short) * 786432ULL);
    short* Wt1  = (short*)take(sizeof(short) * 131072ULL);
    float* xg1  = (float*)take(sizeof(float) * (size_t)N_GENE * H0);
    float* xd1  = (float*)take(sizeof(float) * (size_t)N_DRUG * H0);
    float* dinv_g = (float*)take(sizeof(float) * N_GENE);
    float* dinv_d = (float*)take(sizeof(float) * N_DRUG);
    int* cnt   = (int*)take(4 * 46000);
    int* tmp   = (int*)take(4 * 46000);
    int* bsum  = (int*)take(4 * 64);
    int* pos   = (int*)take(4 * 46000);
    int* rpall = (int*)take(4 * 46001);
    int* col   = (int*)take(4 * 1020000);

    const int* rp_gg = rpall;
    const int* rp_dd = rpall + 20000;
    const int* rp_dt = rpall + 23000;
    const int* rp_td = rpall + 43000;

    // ---- CSR build + L0 weight cast ----
    hipMemsetAsync(cnt, 0, 4 * 46000, stream);
    CastT4P tp0 = {262144u, 524288u, 655360u, 786432u, 10, 10, 9, 9, H0};
    int countBlocks = (1020000 + 255) / 256;
    count4x_kernel<<<countBlocks + (786432 + 255) / 256, 256, 0, stream>>>(
        ei_gg, ei_dd, ei_dt, ei_td, cnt, W0gg, W0td, W0dd, W0dt, Wt0, tp0, countBlocks);
    scan_p1<<<45, 1024, 0, stream>>>(cnt, tmp, bsum);
    scan_p2<<<1, 64, 0, stream>>>(bsum);
    scan_p3<<<45, 1024, 0, stream>>>(cnt, tmp, bsum, rpall, pos, dinv_g, dinv_d);
    fill_kernel<<<(1020000 + 255) / 256, 256, 0, stream>>>(ei_gg, ei_dd, ei_dt, ei_td, pos, col);

    // block ranges (BM=32): gg 625, td 625, dd 94, dt 94 -> 1438 blocks
    // ================= layer 0 (fused dropout GEMM, BN=256) =================
    {
        GDescF g0 = {gene, 0u,      0u,        dinv_g,  N_GENE, 1024, 0,    dk[0][0], dk[0][1]};
        GDescF g1 = {gene, 262144u, 5120000u,  nullptr, N_GENE, 1024, 625,  dk[3][0], dk[3][1]};
        GDescF g2 = {drug, 524288u, 10240000u, dinv_d,  N_DRUG, 512,  1250, dk[1][0], dk[1][1]};
        GDescF g3 = {drug, 655360u, 11008000u, nullptr, N_DRUG, 512,  1344, dk[2][0], dk[2][1]};
        gemmf_kernel<256><<<1438, 256, 0, stream>>>(Wt0, XW, g0, g1, g2, g3);

        AggP pg = {XW, rp_gg, dinv_g, b0gg, XW + 11008000, rp_dt, b0dt, xg1, N_GENE};
        AggP pd = {XW + 10240000, rp_dd, dinv_d, b0dd, XW + 5120000, rp_td, b0td, xd1, N_DRUG};
        CastT4P tp1 = {32768u, 65536u, 98304u, 131072u, 8, 8, 8, 8, H1};
        int geneBlocks = (N_GENE + 3) / 4, aggBlocks = geneBlocks + (N_DRUG + 3) / 4;
        agg2x_kernel<4, true><<<aggBlocks + (131072 + 255) / 256, 256, 0, stream>>>(
            pg, pd, col, geneBlocks, aggBlocks, W1gg, W1td, W1dd, W1dt, Wt1, tp1);
    }

    // ================= layer 1 (fused dropout GEMM, BN=128) =================
    {
        GDescF g0 = {xg1, 0u,     0u,        dinv_g,  N_GENE, 256, 0,    dk[4][0], dk[4][1]};
        GDescF g1 = {xg1, 32768u, 5120000u,  nullptr, N_GENE, 256, 625,  dk[7][0], dk[7][1]};
        GDescF g2 = {xd1, 65536u, 10240000u, dinv_d,  N_DRUG, 256, 1250, dk[5][0], dk[5][1]};
        GDescF g3 = {xd1, 98304u, 11008000u, nullptr, N_DRUG, 256, 1344, dk[6][0], dk[6][1]};
        gemmf_kernel<128><<<1438, 256, 0, stream>>>(Wt1, XW, g0, g1, g2, g3);

        float* og = (float*)d_out;
        float* od = og + (size_t)N_GENE * H1;
        AggP pg = {XW, rp_gg, dinv_g, b1gg, XW + 11008000, rp_dt, b1dt, og, N_GENE};
        AggP pd = {XW + 10240000, rp_dd, dinv_d, b1dd, XW + 5120000, rp_td, b1td, od, N_DRUG};
        CastT4P tpDummy = {0u, 0u, 0u, 0u, 0, 0, 0, 0, 0};
        int geneBlocks = (N_GENE + 3) / 4, aggBlocks = geneBlocks + (N_DRUG + 3) / 4;
        agg2x_kernel<2, false><<<aggBlocks, 256, 0, stream>>>(
            pg, pd, col, geneBlocks, aggBlocks,
            nullptr, nullptr, nullptr, nullptr, nullptr, tpDummy);
    }
}